// Round 3
// baseline (361.593 us; speedup 1.0000x reference)
//
#include <hip/hip_runtime.h>
#include <stdint.h>

#define KWORDS 128   // 4096 bits / 32 per row

// quad swizzle within a 64B row: spreads rows {r, r+8, r+16, r+24} across
// distinct bank-quads -> a-reads conflict-free, w-reads <=2-way (free).
__device__ __forceinline__ uint32_t swz(int row) {
    return (uint32_t)(((row >> 1) ^ (row >> 3)) & 3);
}

// popcount-accumulate: LLVM folds add(ctpop(x), acc) -> v_bcnt_u32_b32 x, acc
__device__ __forceinline__ void xpc(int& acc, uint32_t a, uint32_t w) {
    acc = (int)__popc(a ^ w) + acc;
}

// ---------------- pack kernels: 1 output word (32 elems) per thread ----------
__global__ __launch_bounds__(256)
void pack_f32_k(const float* __restrict__ in, uint32_t* __restrict__ out) {
    size_t t = (size_t)blockIdx.x * 256 + threadIdx.x;
    const float4* p = (const float4*)(in + t * 32);
    uint32_t w = 0;
    #pragma unroll
    for (int q = 0; q < 8; ++q) {
        float4 v = p[q];
        w |= (v.x >= 0.0f ? 1u : 0u) << (4*q + 0);
        w |= (v.y >= 0.0f ? 1u : 0u) << (4*q + 1);
        w |= (v.z >= 0.0f ? 1u : 0u) << (4*q + 2);
        w |= (v.w >= 0.0f ? 1u : 0u) << (4*q + 3);
    }
    out[t] = w;
}

__global__ __launch_bounds__(256)
void pack_i32_k(const int* __restrict__ in, uint32_t* __restrict__ out) {
    size_t t = (size_t)blockIdx.x * 256 + threadIdx.x;
    const int4* p = (const int4*)(in + t * 32);
    uint32_t w = 0;
    #pragma unroll
    for (int q = 0; q < 8; ++q) {
        int4 v = p[q];   // values in {0,1}
        w |= (uint32_t)(v.x & 1) << (4*q + 0);
        w |= (uint32_t)(v.y & 1) << (4*q + 1);
        w |= (uint32_t)(v.z & 1) << (4*q + 2);
        w |= (uint32_t)(v.w & 1) << (4*q + 3);
    }
    out[t] = w;
}

// ---------------- popcount GEMM ----------------
// C[b,n] = 4096 - sum_w popc(A[b,w] ^ W[n,w]); A: Mx128 words, W: Nx128 words.
// BM=16*RT rows, BN=16*NJ cols, 256 threads, RTxNJ outputs/thread.
// Double-buffered LDS, one barrier per K-chunk.
// PACK_OUT: emit bit (match >= thr) packed into Mx(N/32) words (layer 1).

template<int RT, int NJ, bool PACK_OUT>
__global__ __launch_bounds__(256, 2)
void bnn_gemm(const uint32_t* __restrict__ A,
              const uint32_t* __restrict__ W,
              int N,
              const int* __restrict__ thr_ptr,
              uint32_t* __restrict__ out_pack,
              int* __restrict__ out_i32)
{
    constexpr int BM   = 16 * RT;
    constexpr int BN   = 16 * NJ;
    constexpr int CK   = 16;               // words per K-chunk (64B per row)
    constexpr int NCH  = KWORDS / CK;      // 8 chunks
    constexpr int ROWS = BM + BN;          // staged rows (A then W)
    constexpr int NIT  = ROWS / 64;        // quads per thread per chunk (exact)

    __shared__ uint32_t lds[2][ROWS * CK]; // 64B/row, quad-swizzled, dbuf

    const int tid = threadIdx.x;
    const int th  = tid & 15;              // cols th + 16*j
    const int tb  = tid >> 4;              // rows tb*RT + i
    const int bm  = blockIdx.y;
    const int bn  = blockIdx.x;

    const uint32_t* Ab = A + (size_t)(bm * BM) * KWORDS;
    const uint32_t* Wb = W + (size_t)(bn * BN) * KWORDS;

    int acc[RT][NJ];
    #pragma unroll
    for (int i = 0; i < RT; ++i)
        #pragma unroll
        for (int j = 0; j < NJ; ++j) acc[i][j] = 0;

    // swizzled LDS read bases (byte offsets within a buffer); quad kw4 at base^(kw4<<4)
    uint32_t abase[RT], wbase[NJ];
    #pragma unroll
    for (int i = 0; i < RT; ++i) {
        int r = tb * RT + i;
        abase[i] = (uint32_t)(r * 64) | (swz(r) << 4);
    }
    #pragma unroll
    for (int j = 0; j < NJ; ++j) {
        int r = th + 16 * j;
        wbase[j] = (uint32_t)((BM + r) * 64) | (swz(r) << 4);
    }

    // per-thread staging slots (constant across chunks)
    int srow[NIT];
    const uint32_t* sptr[NIT];
    uint32_t sdst[NIT];
    #pragma unroll
    for (int it = 0; it < NIT; ++it) {
        int idx = tid + 256 * it;
        int row = idx >> 2, q = idx & 3;
        srow[it] = row;
        sptr[it] = (row < BM) ? (Ab + (size_t)row * KWORDS + q * 4)
                              : (Wb + (size_t)(row - BM) * KWORDS + q * 4);
        sdst[it] = (uint32_t)(row * 64) + (((uint32_t)q ^ swz(row)) << 4);
    }

    uint4 pre[NIT];
    auto ldchunk = [&](int ck) {
        #pragma unroll
        for (int it = 0; it < NIT; ++it)
            pre[it] = *(const uint4*)(sptr[it] + ck * CK);
    };
    auto wrchunk = [&](int buf) {
        #pragma unroll
        for (int it = 0; it < NIT; ++it)
            *(uint4*)((char*)lds[buf] + sdst[it]) = pre[it];
    };

    ldchunk(0);
    wrchunk(0);
    __syncthreads();

    int cur = 0;
    for (int ck = 0; ck < NCH; ++ck) {
        if (ck + 1 < NCH) ldchunk(ck + 1);   // issue early: HBM latency hides under compute

        #pragma unroll
        for (int kw4 = 0; kw4 < 4; ++kw4) {
            uint4 a4[RT], w4[NJ];
            #pragma unroll
            for (int i = 0; i < RT; ++i)
                a4[i] = *(const uint4*)((char*)lds[cur] + (abase[i] ^ (uint32_t)(kw4 << 4)));
            #pragma unroll
            for (int j = 0; j < NJ; ++j)
                w4[j] = *(const uint4*)((char*)lds[cur] + (wbase[j] ^ (uint32_t)(kw4 << 4)));
            #pragma unroll
            for (int i = 0; i < RT; ++i)
                #pragma unroll
                for (int j = 0; j < NJ; ++j) {
                    xpc(acc[i][j], a4[i].x, w4[j].x);
                    xpc(acc[i][j], a4[i].y, w4[j].y);
                    xpc(acc[i][j], a4[i].z, w4[j].z);
                    xpc(acc[i][j], a4[i].w, w4[j].w);
                }
        }

        if (ck + 1 < NCH) {
            wrchunk(cur ^ 1);                // write-late into the other buffer
            __syncthreads();
            cur ^= 1;
        }
    }

    if constexpr (PACK_OUT) {
        const int thr = *thr_ptr;
        // reuse buffer 0 as bit matrix: BM*BN bytes == ROWS*CK*4 when RT==NJ==8
        uint8_t* bits = (uint8_t*)lds[0];
        #pragma unroll
        for (int i = 0; i < RT; ++i)
            #pragma unroll
            for (int j = 0; j < NJ; ++j) {
                int match = 4096 - acc[i][j];
                bits[(tb * RT + i) * BN + th + 16 * j] = (match >= thr) ? 1 : 0;
            }
        __syncthreads();
        // pack BM rows x BN/32 words; BM*BN/32 words, spread over 256 threads
        constexpr int WPT = (BM * BN / 32) / 256;   // 2 for 128x128
        #pragma unroll
        for (int it = 0; it < WPT; ++it) {
            int idx = tid + it * 256;
            int row = idx / (BN / 32), wq = idx % (BN / 32);
            const uint32_t* p = (const uint32_t*)(bits + row * BN + wq * 32);
            uint32_t word = 0;
            #pragma unroll
            for (int m = 0; m < 8; ++m) {
                uint32_t v = p[m] & 0x01010101u;
                word |= (((v * 0x01020408u) >> 24) & 0xFu) << (4 * m);
            }
            out_pack[(size_t)(bm * BM + row) * (N >> 5) + bn * (BN / 32) + wq] = word;
        }
    } else {
        #pragma unroll
        for (int i = 0; i < RT; ++i) {
            int b = bm * BM + tb * RT + i;
            #pragma unroll
            for (int j = 0; j < NJ; ++j) {
                int h = bn * BN + th + 16 * j;
                out_i32[(size_t)b * N + h] = 4096 - acc[i][j];
            }
        }
    }
}

extern "C" void kernel_launch(void* const* d_in, const int* in_sizes, int n_in,
                              void* d_out, int out_size, void* d_ws, size_t ws_size,
                              hipStream_t stream) {
    const float* x   = (const float*)d_in[0];
    const int*   w1  = (const int*)d_in[1];
    const int*   w2  = (const int*)d_in[2];
    const int*   thr = (const int*)d_in[3];
    int* out = (int*)d_out;

    const int B = 2048, IN = 4096, H = 4096, OUT = 1024;

    uint8_t* ws = (uint8_t*)d_ws;
    uint32_t* xpack   = (uint32_t*)(ws);                 // B  *128 w = 1.0 MB
    uint32_t* w1pack  = (uint32_t*)(ws + (1u << 20));    // H  *128 w = 2.0 MB
    uint32_t* w2pack  = (uint32_t*)(ws + (3u << 20));    // OUT*128 w = 0.5 MB
    uint32_t* actpack = (uint32_t*)(ws + (7u << 19));    // B  *128 w = 1.0 MB

    pack_f32_k<<<B * IN  / 32 / 256, 256, 0, stream>>>(x,  xpack);
    pack_i32_k<<<H * IN  / 32 / 256, 256, 0, stream>>>(w1, w1pack);
    pack_i32_k<<<OUT * H / 32 / 256, 256, 0, stream>>>(w2, w2pack);

    dim3 g1(H / 128, B / 128);   // 32 x 16 = 512 blocks, 2/CU
    bnn_gemm<8, 8, true><<<g1, 256, 0, stream>>>(xpack, w1pack, H, thr, actpack, nullptr);

    dim3 g2(OUT / 64, B / 64);   // 16 x 32 = 512 blocks, 2/CU
    bnn_gemm<4, 4, false><<<g2, 256, 0, stream>>>(actpack, w2pack, OUT, nullptr, nullptr, out);
}

// Round 4
// 118.803 us; speedup vs baseline: 3.0436x; 3.0436x over previous
//
#include <hip/hip_runtime.h>
#include <stdint.h>

#define KWORDS 128   // 4096 bits / 32 per row

// quad swizzle within a 64B row: spreads rows {r, r+8, r+16, r+24} across
// distinct bank-quads -> a-reads conflict-free, w-reads <=2-way (free).
__device__ __forceinline__ uint32_t swz(uint32_t row) {
    return ((row >> 1) ^ (row >> 3)) & 3u;
}

// popcount-accumulate: LLVM folds add(ctpop(x), acc) -> v_bcnt_u32_b32 x, acc
__device__ __forceinline__ void xpc(int& acc, uint32_t a, uint32_t w) {
    acc = (int)__popc(a ^ w) + acc;
}

// direct global->LDS DMA, 16B per lane; LDS dest is wave-uniform base + lane*16
__device__ __forceinline__ void gload_lds16(const void* g, void* l) {
    __builtin_amdgcn_global_load_lds(
        (const __attribute__((address_space(1))) void*)g,
        (__attribute__((address_space(3))) void*)l,
        16, 0, 0);
}

// ---------------- pack kernels: 1 output word (32 elems) per thread ----------
__global__ __launch_bounds__(256)
void pack_f32_k(const float* __restrict__ in, uint32_t* __restrict__ out) {
    size_t t = (size_t)blockIdx.x * 256 + threadIdx.x;
    const float4* p = (const float4*)(in + t * 32);
    uint32_t w = 0;
    #pragma unroll
    for (int q = 0; q < 8; ++q) {
        float4 v = p[q];
        w |= (v.x >= 0.0f ? 1u : 0u) << (4*q + 0);
        w |= (v.y >= 0.0f ? 1u : 0u) << (4*q + 1);
        w |= (v.z >= 0.0f ? 1u : 0u) << (4*q + 2);
        w |= (v.w >= 0.0f ? 1u : 0u) << (4*q + 3);
    }
    out[t] = w;
}

__global__ __launch_bounds__(256)
void pack_i32_k(const int* __restrict__ in, uint32_t* __restrict__ out) {
    size_t t = (size_t)blockIdx.x * 256 + threadIdx.x;
    const int4* p = (const int4*)(in + t * 32);
    uint32_t w = 0;
    #pragma unroll
    for (int q = 0; q < 8; ++q) {
        int4 v = p[q];   // values in {0,1}
        w |= (uint32_t)(v.x & 1) << (4*q + 0);
        w |= (uint32_t)(v.y & 1) << (4*q + 1);
        w |= (uint32_t)(v.z & 1) << (4*q + 2);
        w |= (uint32_t)(v.w & 1) << (4*q + 3);
    }
    out[t] = w;
}

// ---------------- popcount GEMM ----------------
// C[b,n] = 4096 - sum_w popc(A[b,w] ^ W[n,w]); A: Mx128 words, W: Nx128 words.
// BM=16*RT rows, BN=16*NJ cols, 256 threads, RTxNJ outputs/thread.
// global_load_lds staging (pre-swizzled source, linear LDS dest), double-buffered,
// one barrier per K-chunk (m97 structure).

template<int RT, int NJ, bool PACK_OUT>
__global__ __launch_bounds__(256, 2)
void bnn_gemm(const uint32_t* __restrict__ A,
              const uint32_t* __restrict__ W,
              int N,
              const int* __restrict__ thr_ptr,
              uint32_t* __restrict__ out_pack,
              int* __restrict__ out_i32)
{
    constexpr int BM   = 16 * RT;
    constexpr int BN   = 16 * NJ;
    constexpr int CK   = 16;                   // words per K-chunk row (64B)
    constexpr int NCH  = KWORDS / CK;          // 8 chunks
    constexpr int ROWS = BM + BN;              // staged rows (A then W)
    constexpr int NST  = ROWS / 64;            // gload_lds calls/thread/chunk
    constexpr uint32_t BUFSZ = (uint32_t)(ROWS * CK * 4);   // pow2: 16K / 8K

    __shared__ uint32_t lds[2][ROWS * CK];     // 64B/row, quad-swizzled slots

    const int tid  = threadIdx.x;
    const int lane = tid & 63;
    const int wave = __builtin_amdgcn_readfirstlane(tid >> 6);
    const int th   = tid & 15;                 // cols th + 16*j
    const int tb   = tid >> 4;                 // rows tb*RT + i
    const int bm   = blockIdx.y;
    const int bn   = blockIdx.x;

    const uint8_t* Ab = (const uint8_t*)(A + (size_t)bm * BM * KWORDS);
    const uint8_t* Wb = (const uint8_t*)(W + (size_t)bn * BN * KWORDS);

    // per-lane pre-swizzled global source pointers (advance +64B per chunk)
    const uint8_t* gp[NST];
    #pragma unroll
    for (int t = 0; t < NST; ++t) {
        uint32_t row = (uint32_t)(wave * (ROWS / 4) + t * 16) + ((uint32_t)lane >> 2);
        uint32_t q   = ((uint32_t)lane & 3u) ^ swz(row);
        gp[t] = (row < (uint32_t)BM ? Ab + (size_t)row * (KWORDS * 4)
                                    : Wb + (size_t)(row - BM) * (KWORDS * 4)) + q * 16;
    }
    const uint32_t ldst = (uint32_t)(wave * (ROWS / 4) * 64);  // wave-uniform dest off

    // swizzled LDS read addresses, absolute (include buffer bit), 4 variants each:
    // a(i,kw4)  = AX[(((i>>1)&(RT/2-1)) ^ kw4) & 3] + i*64
    // w(j,kw4)  = WX[((2*(j&1)) ^ kw4) & 3]        + j*1024
    uint32_t AX[4], WX[4];
    {
        uint32_t sa = swz((uint32_t)(tb * RT));
        uint32_t sw = swz((uint32_t)th);
        #pragma unroll
        for (int v = 0; v < 4; ++v) {
            AX[v] = (uint32_t)(tb * RT * 64) | (((sa ^ (uint32_t)v) & 3u) << 4);
            WX[v] = (uint32_t)((BM + th) * 64) | (((sw ^ (uint32_t)v) & 3u) << 4);
        }
    }

    int acc[RT][NJ];
    #pragma unroll
    for (int i = 0; i < RT; ++i)
        #pragma unroll
        for (int j = 0; j < NJ; ++j) acc[i][j] = 0;

    const uint8_t* ldsr = (const uint8_t*)lds;

    auto stage = [&](int buf) {
        #pragma unroll
        for (int t = 0; t < NST; ++t) {
            gload_lds16(gp[t], (uint8_t*)lds + (uint32_t)buf * BUFSZ + ldst
                                 + (uint32_t)(t * 1024));
            gp[t] += 64;
        }
    };

    stage(0);
    __syncthreads();   // compiler drains vmcnt(0) before s_barrier

    #pragma unroll 1
    for (int ck = 0; ck < NCH; ++ck) {
        if (ck + 1 < NCH) stage((ck & 1) ^ 1);   // fill other buffer; latency hides
        #pragma unroll
        for (int kw4 = 0; kw4 < 4; ++kw4) {
            uint4 w4[NJ];
            #pragma unroll
            for (int j = 0; j < NJ; ++j)
                w4[j] = *(const uint4*)(ldsr + WX[((2 * (j & 1)) ^ kw4) & 3] + j * 1024);
            #pragma unroll
            for (int i = 0; i < RT; ++i) {
                uint4 a = *(const uint4*)(ldsr + AX[(((i >> 1) & (RT/2 - 1)) ^ kw4) & 3] + i * 64);
                #pragma unroll
                for (int j = 0; j < NJ; ++j) {
                    xpc(acc[i][j], a.x, w4[j].x);
                    xpc(acc[i][j], a.y, w4[j].y);
                    xpc(acc[i][j], a.z, w4[j].z);
                    xpc(acc[i][j], a.w, w4[j].w);
                }
            }
        }
        __syncthreads();
        #pragma unroll
        for (int v = 0; v < 4; ++v) { AX[v] ^= BUFSZ; WX[v] ^= BUFSZ; }  // flip buffer
    }

    if constexpr (PACK_OUT) {
        const int thr = *thr_ptr;
        // last compute read lds[1] (NCH even); lds[0] is free: BM*BN bytes == BUFSZ
        uint8_t* bits = (uint8_t*)lds[0];
        #pragma unroll
        for (int i = 0; i < RT; ++i)
            #pragma unroll
            for (int j = 0; j < NJ; ++j) {
                int match = 4096 - acc[i][j];
                bits[(tb * RT + i) * BN + th + 16 * j] = (match >= thr) ? 1 : 0;
            }
        __syncthreads();
        constexpr int WPT = (BM * BN / 32) / 256;   // 2 for 128x128
        #pragma unroll
        for (int it = 0; it < WPT; ++it) {
            int idx = tid + it * 256;
            int row = idx / (BN / 32), wq = idx % (BN / 32);
            const uint32_t* p = (const uint32_t*)(bits + row * BN + wq * 32);
            uint32_t word = 0;
            #pragma unroll
            for (int m = 0; m < 8; ++m) {
                uint32_t v = p[m] & 0x01010101u;
                word |= (((v * 0x01020408u) >> 24) & 0xFu) << (4 * m);
            }
            out_pack[(size_t)(bm * BM + row) * (N >> 5) + bn * (BN / 32) + wq] = word;
        }
    } else {
        #pragma unroll
        for (int i = 0; i < RT; ++i) {
            int b = bm * BM + tb * RT + i;
            #pragma unroll
            for (int j = 0; j < NJ; ++j) {
                int h = bn * BN + th + 16 * j;
                out_i32[(size_t)b * N + h] = 4096 - acc[i][j];
            }
        }
    }
}

extern "C" void kernel_launch(void* const* d_in, const int* in_sizes, int n_in,
                              void* d_out, int out_size, void* d_ws, size_t ws_size,
                              hipStream_t stream) {
    const float* x   = (const float*)d_in[0];
    const int*   w1  = (const int*)d_in[1];
    const int*   w2  = (const int*)d_in[2];
    const int*   thr = (const int*)d_in[3];
    int* out = (int*)d_out;

    const int B = 2048, IN = 4096, H = 4096, OUT = 1024;

    uint8_t* ws = (uint8_t*)d_ws;
    uint32_t* xpack   = (uint32_t*)(ws);                 // B  *128 w = 1.0 MB
    uint32_t* w1pack  = (uint32_t*)(ws + (1u << 20));    // H  *128 w = 2.0 MB
    uint32_t* w2pack  = (uint32_t*)(ws + (3u << 20));    // OUT*128 w = 0.5 MB
    uint32_t* actpack = (uint32_t*)(ws + (7u << 19));    // B  *128 w = 1.0 MB

    pack_f32_k<<<B * IN  / 32 / 256, 256, 0, stream>>>(x,  xpack);
    pack_i32_k<<<H * IN  / 32 / 256, 256, 0, stream>>>(w1, w1pack);
    pack_i32_k<<<OUT * H / 32 / 256, 256, 0, stream>>>(w2, w2pack);

    dim3 g1(H / 128, B / 128);   // 32 x 16 = 512 blocks
    bnn_gemm<8, 8, true><<<g1, 256, 0, stream>>>(xpack, w1pack, H, thr, actpack, nullptr);

    dim3 g2(OUT / 64, B / 64);   // 16 x 32 = 512 blocks
    bnn_gemm<4, 4, false><<<g2, 256, 0, stream>>>(actpack, w2pack, OUT, nullptr, nullptr, out);
}